// Round 1
// baseline (163.490 us; speedup 1.0000x reference)
//
#include <hip/hip_runtime.h>

typedef __attribute__((__ext_vector_type__(8))) __bf16 bf16x8;
typedef __attribute__((__ext_vector_type__(4))) float f32x4;
typedef __attribute__((__ext_vector_type__(4))) int i32x4;

#define HW 56
#define HW2 3136
#define CIN 128
#define COUT 256
#define NB 32
#define NPIX 100352  // 32*3136

static __device__ __forceinline__ unsigned short f2bf(float f) {
  unsigned u = __float_as_uint(f);
  u += 0x7fff + ((u >> 16) & 1);
  return (unsigned short)(u >> 16);
}

// ---- prep_x: x NCHW f32 -> x_t NHWC bf16, plus channel-sum xs ----
__global__ __launch_bounds__(256) void prep_x(const float* __restrict__ x,
                                              unsigned short* __restrict__ x_t,
                                              float* __restrict__ xs) {
  __shared__ float tile[CIN * 57];  // [c][w], stride 57 kills bank conflicts
  const int bh = blockIdx.x;        // b*56 + h
  const float* src = x + (size_t)(bh / HW) * CIN * HW2 + (size_t)(bh % HW) * HW;
  for (int idx = threadIdx.x; idx < CIN * HW; idx += 256) {
    int c = idx / HW, w = idx - c * HW;
    tile[c * 57 + w] = src[(size_t)c * HW2 + w];
  }
  __syncthreads();
  unsigned short* dst = x_t + (size_t)bh * HW * CIN;
  for (int idx = threadIdx.x; idx < HW * (CIN / 2); idx += 256) {
    int w = idx >> 6;            // pixel within row
    int c = (idx & 63) << 1;     // channel pair
    unsigned lo = f2bf(tile[c * 57 + w]);
    unsigned hi = f2bf(tile[(c + 1) * 57 + w]);
    *reinterpret_cast<unsigned*>(&dst[w * CIN + c]) = lo | (hi << 16);
  }
  if (threadIdx.x < HW) {
    float s = 0.f;
    for (int c = 0; c < CIN; ++c) s += tile[c * 57 + threadIdx.x];
    xs[(size_t)bh * HW + threadIdx.x] = s;
  }
}

// ---- prep_w: core [COUT][CIN][3][3] f32 -> w_t [COUT][9][CIN] bf16 ----
__global__ __launch_bounds__(256) void prep_w(const float* __restrict__ core,
                                              unsigned short* __restrict__ w_t) {
  int i = blockIdx.x * 256 + threadIdx.x;  // < 256*9*128
  int c = i & 127;
  int p = (i >> 7) % 9;
  int m = i / (9 * 128);
  w_t[i] = f2bf(core[(size_t)(m * CIN + c) * 9 + p]);
}

// ---- periphery stencil on xs ----
__global__ __launch_bounds__(256) void periph_k(const float* __restrict__ xs,
                                                const float* __restrict__ per,
                                                float* __restrict__ po) {
  int n = blockIdx.x * 256 + threadIdx.x;
  int b = n / HW2, r = n - b * HW2;
  int ho = r / HW, wo = r - ho * HW;
  const float* xb = xs + (size_t)b * HW2;
  const int pdy[16] = {0,0,0,0,0,1,1,2,2,3,3,4,4,4,4,4};
  const int pdx[16] = {0,1,2,3,4,0,4,0,4,0,4,0,1,2,3,4};
  float acc = 0.f;
#pragma unroll
  for (int t = 0; t < 16; ++t) {
    int h = ho + pdy[t] - 2, w = wo + pdx[t] - 2;
    if ((unsigned)h < HW && (unsigned)w < HW) acc += per[t] * xb[h * HW + w];
  }
  po[n] = acc;
}

// ---- implicit-GEMM conv + fused gate epilogue ----
// Tile: BM=128 (cout), BN=128 (pixels), BK=64 (c-chunk); K-steps = 9 taps * 2 chunks.
// LDS tiles [row][64 bf16] with XOR swizzle byte ^= (row&7)<<4 (2-way max aliasing).
__global__ __launch_bounds__(256) void gemm_k(const unsigned short* __restrict__ x_t,
                                              const unsigned short* __restrict__ w_t,
                                              const float* __restrict__ po,
                                              const float* __restrict__ thresh,
                                              const float* __restrict__ scale,
                                              float* __restrict__ out) {
  __shared__ __align__(16) char sA[128 * 128];
  __shared__ __align__(16) char sB[128 * 128];
  __shared__ float sTh[128];

  const int tid = threadIdx.x;
  const int lane = tid & 63;
  const int wid = tid >> 6;
  const int wm = wid >> 1, wn = wid & 1;
  const int m0 = (blockIdx.x & 1) * 128;
  const int n0 = (blockIdx.x >> 1) * 128;

  if (tid < 128) sTh[tid] = thresh[m0 + tid];

  const int lc = tid & 7;      // 16B slot within a 128B row
  const int rowi = tid >> 3;   // 0..31

  int jb[4], jh[4], jw[4], swo[4];
  size_t awsrc[4];
#pragma unroll
  for (int it = 0; it < 4; ++it) {
    int j = it * 32 + rowi;          // LDS row (pixel for B, cout for A)
    int n = n0 + j;
    int b = n / HW2;
    int r = n - b * HW2;
    int h = r / HW;
    jb[it] = b; jh[it] = h; jw[it] = r - h * HW;
    swo[it] = j * 128 + ((lc * 16) ^ ((j & 7) << 4));
    awsrc[it] = (size_t)(m0 + j) * (9 * CIN) + lc * 8;
  }

  int aro[4][2], bro[4][2];
#pragma unroll
  for (int i = 0; i < 4; ++i) {
#pragma unroll
    for (int ko = 0; ko < 2; ++ko) {
      int rowA = wm * 64 + i * 16 + (lane & 15);
      int rowB = wn * 64 + i * 16 + (lane & 15);
      int bocol = ko * 64 + ((lane >> 4) << 4);  // byte offset of 8-elem k-group
      aro[i][ko] = rowA * 128 + (bocol ^ ((rowA & 7) << 4));
      bro[i][ko] = rowB * 128 + (bocol ^ ((rowB & 7) << 4));
    }
  }

  f32x4 acc[4][4] = {};

  for (int step = 0; step < 18; ++step) {
    const int p = step >> 1;           // tap index 0..8 (kh*3+kw)
    const int c0 = (step & 1) << 6;    // channel chunk 0/64
    const int dy = p / 3 - 1;
    const int dx = p - (p / 3) * 3 - 1;
    __syncthreads();
#pragma unroll
    for (int it = 0; it < 4; ++it) {
      i32x4 av = *reinterpret_cast<const i32x4*>(w_t + awsrc[it] + p * CIN + c0);
      *reinterpret_cast<i32x4*>(sA + swo[it]) = av;
    }
#pragma unroll
    for (int it = 0; it < 4; ++it) {
      int h = jh[it] + dy, w = jw[it] + dx;
      i32x4 bv = {0, 0, 0, 0};
      if ((unsigned)h < HW && (unsigned)w < HW)
        bv = *reinterpret_cast<const i32x4*>(
            x_t + ((size_t)((jb[it] * HW + h) * HW + w) << 7) + c0 + lc * 8);
      *reinterpret_cast<i32x4*>(sB + swo[it]) = bv;
    }
    __syncthreads();
#pragma unroll
    for (int ko = 0; ko < 2; ++ko) {
      bf16x8 af[4], bfr[4];
#pragma unroll
      for (int i = 0; i < 4; ++i)
        af[i] = *reinterpret_cast<const bf16x8*>(sA + aro[i][ko]);
#pragma unroll
      for (int i = 0; i < 4; ++i)
        bfr[i] = *reinterpret_cast<const bf16x8*>(sB + bro[i][ko]);
#pragma unroll
      for (int i = 0; i < 4; ++i)
#pragma unroll
        for (int j = 0; j < 4; ++j)
          acc[i][j] = __builtin_amdgcn_mfma_f32_16x16x32_bf16(af[i], bfr[j], acc[i][j], 0, 0, 0);
    }
  }

  const float sc = scale[0];
#pragma unroll
  for (int nj = 0; nj < 4; ++nj) {
    int nl = wn * 64 + nj * 16 + (lane & 15);
    int n = n0 + nl;
    int b = n / HW2;
    int r = n - b * HW2;   // ho*56+wo
    float pv = po[n];
    float* op = out + (size_t)b * (COUT * HW2) + r;
#pragma unroll
    for (int mi = 0; mi < 4; ++mi) {
      int cl = wm * 64 + mi * 16 + ((lane >> 4) << 2);  // local cout base
#pragma unroll
      for (int q = 0; q < 4; ++q) {
        float cv = acc[mi][nj][q];
        float th = sTh[cl + q];
        float g = 1.f / (1.f + __expf(-sc * (cv - th)));
        op[(size_t)(m0 + cl + q) * HW2] = cv + g * pv;
      }
    }
  }
}

extern "C" void kernel_launch(void* const* d_in, const int* in_sizes, int n_in,
                              void* d_out, int out_size, void* d_ws, size_t ws_size,
                              hipStream_t stream) {
  (void)in_sizes; (void)n_in; (void)out_size; (void)ws_size;
  const float* x      = (const float*)d_in[0];
  const float* core   = (const float*)d_in[1];
  const float* per    = (const float*)d_in[2];
  const float* thresh = (const float*)d_in[3];
  const float* scale  = (const float*)d_in[4];
  float* out = (float*)d_out;

  char* ws = (char*)d_ws;
  unsigned short* x_t = (unsigned short*)ws;                    // 25,690,112 B
  unsigned short* w_t = (unsigned short*)(ws + 25690112);       //    589,824 B
  float* xs           = (float*)(ws + 26279936);                //    401,408 B
  float* po           = (float*)(ws + 26681344);                //    401,408 B

  prep_x<<<NB * HW, 256, 0, stream>>>(x, x_t, xs);
  prep_w<<<(COUT * 9 * CIN) / 256, 256, 0, stream>>>(core, w_t);
  periph_k<<<NPIX / 256, 256, 0, stream>>>(xs, per, po);
  gemm_k<<<2 * (NPIX / 128), 256, 0, stream>>>(x_t, w_t, po, thresh, scale, out);
}

// Round 2
// 141.204 us; speedup vs baseline: 1.1578x; 1.1578x over previous
//
#include <hip/hip_runtime.h>

typedef __attribute__((__ext_vector_type__(8))) _Float16 f16x8;
typedef __attribute__((__ext_vector_type__(4))) float f32x4;
typedef __attribute__((__ext_vector_type__(4))) int i32x4;

#define HW 56
#define HW2 3136
#define CIN 128
#define COUT 256
#define NB 32
#define NPIX 100352  // 32*3136
#define PH 58        // padded spatial dim (1-px halo)

static __device__ __forceinline__ unsigned short f2h(float f) {
  _Float16 h = (_Float16)f;
  return __builtin_bit_cast(unsigned short, h);
}

#define GLD_LDS16(g, l)                                          \
  __builtin_amdgcn_global_load_lds(                              \
      (const __attribute__((address_space(1))) void*)(g),        \
      (__attribute__((address_space(3))) void*)(l), 16, 0, 0)

// ---- zero the 1-pixel halo of x_pad ----
__global__ __launch_bounds__(256) void zero_halo(unsigned short* __restrict__ xp) {
  int t = blockIdx.x * 256 + threadIdx.x;  // 32*228*16 threads
  int ck = t & 15;                          // 16B chunk in 256B pixel
  int pi = t >> 4;
  int b = pi / 228, r = pi - b * 228;
  int h, w;
  if (r < 58) { h = 0; w = r; }
  else if (r < 116) { h = 57; w = r - 58; }
  else { int q = r - 116; h = 1 + (q >> 1); w = (q & 1) * 57; }
  size_t off = (((size_t)(b * PH + h) * PH + w) << 8) + (ck << 4);
  *reinterpret_cast<i32x4*>((char*)xp + off) = (i32x4){0, 0, 0, 0};
}

// ---- prep_x: x NCHW f32 -> x_pad [32][58][58][128] f16 (interior), plus channel-sum xs ----
__global__ __launch_bounds__(256) void prep_x(const float* __restrict__ x,
                                              unsigned short* __restrict__ xp,
                                              float* __restrict__ xs) {
  __shared__ float tile[CIN * 57];  // [c][w], stride 57 kills bank conflicts
  const int bh = blockIdx.x;        // b*56 + h
  const float* src = x + (size_t)(bh / HW) * CIN * HW2 + (size_t)(bh % HW) * HW;
  for (int idx = threadIdx.x; idx < CIN * HW; idx += 256) {
    int c = idx / HW, w = idx - c * HW;
    tile[c * 57 + w] = src[(size_t)c * HW2 + w];
  }
  __syncthreads();
  unsigned short* dst =
      xp + (((size_t)(bh / HW) * PH + (bh % HW) + 1) * PH + 1) * CIN;
  for (int idx = threadIdx.x; idx < HW * (CIN / 2); idx += 256) {
    int w = idx >> 6;         // pixel within row
    int c = (idx & 63) << 1;  // channel pair
    unsigned lo = f2h(tile[c * 57 + w]);
    unsigned hi = f2h(tile[(c + 1) * 57 + w]);
    *reinterpret_cast<unsigned*>(&dst[w * CIN + c]) = lo | (hi << 16);
  }
  if (threadIdx.x < HW) {
    float s = 0.f;
    for (int c = 0; c < CIN; ++c) s += tile[c * 57 + threadIdx.x];
    xs[(size_t)bh * HW + threadIdx.x] = s;
  }
}

// ---- prep_w: core [COUT][CIN][3][3] f32 -> w_t [COUT][9][CIN] f16 ----
__global__ __launch_bounds__(256) void prep_w(const float* __restrict__ core,
                                              unsigned short* __restrict__ w_t) {
  int i = blockIdx.x * 256 + threadIdx.x;  // < 256*9*128
  int c = i & 127;
  int p = (i >> 7) % 9;
  int m = i / (9 * 128);
  w_t[i] = f2h(core[(size_t)(m * CIN + c) * 9 + p]);
}

// ---- periphery stencil on xs ----
__global__ __launch_bounds__(256) void periph_k(const float* __restrict__ xs,
                                                const float* __restrict__ per,
                                                float* __restrict__ po) {
  int n = blockIdx.x * 256 + threadIdx.x;
  int b = n / HW2, r = n - b * HW2;
  int ho = r / HW, wo = r - ho * HW;
  const float* xb = xs + (size_t)b * HW2;
  const int pdy[16] = {0,0,0,0,0,1,1,2,2,3,3,4,4,4,4,4};
  const int pdx[16] = {0,1,2,3,4,0,4,0,4,0,4,0,1,2,3,4};
  float acc = 0.f;
#pragma unroll
  for (int t = 0; t < 16; ++t) {
    int h = ho + pdy[t] - 2, w = wo + pdx[t] - 2;
    if ((unsigned)h < HW && (unsigned)w < HW) acc += per[t] * xb[h * HW + w];
  }
  po[n] = acc;
}

// ---- implicit-GEMM conv + fused gate epilogue (m97-style global_load_lds) ----
// Tile BM=128 (cout) x BN=128 (pixels) x BK=64; 18 K-steps (9 taps x 2 c-chunks).
// LDS linear dest + inverse-swizzled global source + swizzled ds_read (involution
// slot' = slot ^ (row&7)); zero-padded x removes all boundary predicates.
__global__ __launch_bounds__(256) void gemm_k(const unsigned short* __restrict__ xp,
                                              const unsigned short* __restrict__ w_t,
                                              const float* __restrict__ po,
                                              const float* __restrict__ thresh,
                                              const float* __restrict__ scale,
                                              float* __restrict__ out) {
  __shared__ __align__(16) char sA[128 * 128];  // 128 rows x 64 f16
  __shared__ __align__(16) char sB[128 * 128];
  __shared__ float sTh[128];

  const int tid = threadIdx.x;
  const int lane = tid & 63;
  const int wid = tid >> 6;
  const int wm = wid >> 1, wn = wid & 1;
  const int m0 = (blockIdx.x & 1) * 128;
  const int n0 = (blockIdx.x >> 1) * 128;

  if (tid < 128) sTh[tid] = thresh[m0 + tid];

  // staging: per wave 4 x 1KB chunks (8 rows each) for A and for B
  const int jr = lane >> 3;                      // row within 8-row group
  const int sw = (((lane & 7) ^ jr) << 4);       // pre-swizzled 16B slot
  const char* xpc = (const char*)xp;
  const char* wtc = (const char*)w_t;
  int pb[4], ab[4], ldso[4];
#pragma unroll
  for (int i = 0; i < 4; ++i) {
    int j = wid * 32 + i * 8 + jr;
    int n = n0 + j;
    int b = n / HW2, r = n - b * HW2;
    int h = r / HW, w = r - h * HW;
    pb[i] = (((b * PH + h + 1) * PH) + (w + 1)) * 256 + sw;  // center-tap byte addr
    ab[i] = ((m0 + j) * 9) * 256 + sw;
    ldso[i] = (wid * 32 + i * 8) * 128;  // wave-uniform LDS base
  }

  int aro[4][2], bro[4][2];
#pragma unroll
  for (int i = 0; i < 4; ++i) {
#pragma unroll
    for (int ko = 0; ko < 2; ++ko) {
      int rowA = wm * 64 + i * 16 + (lane & 15);
      int rowB = wn * 64 + i * 16 + (lane & 15);
      int bocol = ko * 64 + ((lane >> 4) << 4);
      aro[i][ko] = rowA * 128 + (bocol ^ ((rowA & 7) << 4));
      bro[i][ko] = rowB * 128 + (bocol ^ ((rowB & 7) << 4));
    }
  }

  f32x4 acc[4][4] = {};

  for (int step = 0; step < 18; ++step) {
    const int p = step >> 1;
    const int c0b = (step & 1) << 7;  // channel-chunk byte offset
    const int dy = p / 3 - 1;
    const int dx = p - (p / 3) * 3 - 1;
    const int offB = ((dy * PH + dx) << 8) + c0b;
    const int offA = (p << 8) + c0b;
    __syncthreads();
#pragma unroll
    for (int i = 0; i < 4; ++i) {
      GLD_LDS16(xpc + pb[i] + offB, sB + ldso[i]);
      GLD_LDS16(wtc + ab[i] + offA, sA + ldso[i]);
    }
    __syncthreads();
#pragma unroll
    for (int ko = 0; ko < 2; ++ko) {
      f16x8 af[4], bfr[4];
#pragma unroll
      for (int i = 0; i < 4; ++i)
        af[i] = *reinterpret_cast<const f16x8*>(sA + aro[i][ko]);
#pragma unroll
      for (int i = 0; i < 4; ++i)
        bfr[i] = *reinterpret_cast<const f16x8*>(sB + bro[i][ko]);
#pragma unroll
      for (int i = 0; i < 4; ++i)
#pragma unroll
        for (int j = 0; j < 4; ++j)
          acc[i][j] = __builtin_amdgcn_mfma_f32_16x16x32_f16(af[i], bfr[j], acc[i][j], 0, 0, 0);
    }
  }

  const float sc = scale[0];
#pragma unroll
  for (int nj = 0; nj < 4; ++nj) {
    int nl = wn * 64 + nj * 16 + (lane & 15);
    int n = n0 + nl;
    int b = n / HW2;
    int r = n - b * HW2;  // ho*56+wo
    float pv = po[n];
    float* op = out + (size_t)b * (COUT * HW2) + r;
#pragma unroll
    for (int mi = 0; mi < 4; ++mi) {
      int cl = wm * 64 + mi * 16 + ((lane >> 4) << 2);
#pragma unroll
      for (int q = 0; q < 4; ++q) {
        float cv = acc[mi][nj][q];
        float th = sTh[cl + q];
        float g = 1.f / (1.f + __expf(-sc * (cv - th)));
        op[(size_t)(m0 + cl + q) * HW2] = cv + g * pv;
      }
    }
  }
}

extern "C" void kernel_launch(void* const* d_in, const int* in_sizes, int n_in,
                              void* d_out, int out_size, void* d_ws, size_t ws_size,
                              hipStream_t stream) {
  (void)in_sizes; (void)n_in; (void)out_size; (void)ws_size;
  const float* x      = (const float*)d_in[0];
  const float* core   = (const float*)d_in[1];
  const float* per    = (const float*)d_in[2];
  const float* thresh = (const float*)d_in[3];
  const float* scale  = (const float*)d_in[4];
  float* out = (float*)d_out;

  char* ws = (char*)d_ws;
  unsigned short* xp  = (unsigned short*)ws;                  // 32*58*58*128*2 = 27,557,888 B
  unsigned short* w_t = (unsigned short*)(ws + 27557888);     // 589,824 B
  float* xs           = (float*)(ws + 28147712);              // 401,408 B
  float* po           = (float*)(ws + 28549120);              // 401,408 B

  zero_halo<<<(NB * 228 * 16) / 256, 256, 0, stream>>>(xp);
  prep_x<<<NB * HW, 256, 0, stream>>>(x, xp, xs);
  prep_w<<<(COUT * 9 * CIN) / 256, 256, 0, stream>>>(core, w_t);
  periph_k<<<NPIX / 256, 256, 0, stream>>>(xs, per, po);
  gemm_k<<<2 * (NPIX / 128), 256, 0, stream>>>(xp, w_t, po, thresh, scale, out);
}

// Round 3
// 128.234 us; speedup vs baseline: 1.2749x; 1.1011x over previous
//
#include <hip/hip_runtime.h>

typedef __attribute__((__ext_vector_type__(8))) _Float16 f16x8;
typedef __attribute__((__ext_vector_type__(4))) float f32x4;
typedef __attribute__((__ext_vector_type__(4))) int i32x4;

#define HW 56
#define HW2 3136
#define CIN 128
#define COUT 256
#define NB 32
#define NPIX 100352  // 32*3136
#define PH 58        // padded spatial dim (1-px halo)

static __device__ __forceinline__ unsigned short f2h(float f) {
  _Float16 h = (_Float16)f;
  return __builtin_bit_cast(unsigned short, h);
}

#define GLD_LDS16(g, l)                                          \
  __builtin_amdgcn_global_load_lds(                              \
      (const __attribute__((address_space(1))) void*)(g),        \
      (__attribute__((address_space(3))) void*)(l), 16, 0, 0)

// ---- zero the 1-pixel halo of x_pad ----
__global__ __launch_bounds__(256) void zero_halo(unsigned short* __restrict__ xp) {
  int t = blockIdx.x * 256 + threadIdx.x;  // 32*228*16 threads
  int ck = t & 15;                          // 16B chunk in 256B pixel
  int pi = t >> 4;
  int b = pi / 228, r = pi - b * 228;
  int h, w;
  if (r < 58) { h = 0; w = r; }
  else if (r < 116) { h = 57; w = r - 58; }
  else { int q = r - 116; h = 1 + (q >> 1); w = (q & 1) * 57; }
  size_t off = (((size_t)(b * PH + h) * PH + w) << 8) + (ck << 4);
  *reinterpret_cast<i32x4*>((char*)xp + off) = (i32x4){0, 0, 0, 0};
}

// ---- prep_x: x NCHW f32 -> x_pad [32][58][58][128] f16 (interior), plus channel-sum xs ----
__global__ __launch_bounds__(256) void prep_x(const float* __restrict__ x,
                                              unsigned short* __restrict__ xp,
                                              float* __restrict__ xs) {
  __shared__ float tile[CIN * 57];  // [c][w], stride 57 kills bank conflicts
  const int bh = blockIdx.x;        // b*56 + h
  const float* src = x + (size_t)(bh / HW) * CIN * HW2 + (size_t)(bh % HW) * HW;
  for (int idx = threadIdx.x; idx < CIN * HW; idx += 256) {
    int c = idx / HW, w = idx - c * HW;
    tile[c * 57 + w] = src[(size_t)c * HW2 + w];
  }
  __syncthreads();
  unsigned short* dst =
      xp + (((size_t)(bh / HW) * PH + (bh % HW) + 1) * PH + 1) * CIN;
  for (int idx = threadIdx.x; idx < HW * (CIN / 2); idx += 256) {
    int w = idx >> 6;         // pixel within row
    int c = (idx & 63) << 1;  // channel pair
    unsigned lo = f2h(tile[c * 57 + w]);
    unsigned hi = f2h(tile[(c + 1) * 57 + w]);
    *reinterpret_cast<unsigned*>(&dst[w * CIN + c]) = lo | (hi << 16);
  }
  if (threadIdx.x < HW) {
    float s = 0.f;
    for (int c = 0; c < CIN; ++c) s += tile[c * 57 + threadIdx.x];
    xs[(size_t)bh * HW + threadIdx.x] = s;
  }
}

// ---- prep_w: core [COUT][CIN][3][3] f32 -> w_t [COUT][9][CIN] f16 ----
__global__ __launch_bounds__(256) void prep_w(const float* __restrict__ core,
                                              unsigned short* __restrict__ w_t) {
  int i = blockIdx.x * 256 + threadIdx.x;  // < 256*9*128
  int c = i & 127;
  int p = (i >> 7) % 9;
  int m = i / (9 * 128);
  w_t[i] = f2h(core[(size_t)(m * CIN + c) * 9 + p]);
}

// ---- periphery stencil on xs ----
__global__ __launch_bounds__(256) void periph_k(const float* __restrict__ xs,
                                                const float* __restrict__ per,
                                                float* __restrict__ po) {
  int n = blockIdx.x * 256 + threadIdx.x;
  int b = n / HW2, r = n - b * HW2;
  int ho = r / HW, wo = r - ho * HW;
  const float* xb = xs + (size_t)b * HW2;
  const int pdy[16] = {0,0,0,0,0,1,1,2,2,3,3,4,4,4,4,4};
  const int pdx[16] = {0,1,2,3,4,0,4,0,4,0,4,0,1,2,3,4};
  float acc = 0.f;
#pragma unroll
  for (int t = 0; t < 16; ++t) {
    int h = ho + pdy[t] - 2, w = wo + pdx[t] - 2;
    if ((unsigned)h < HW && (unsigned)w < HW) acc += per[t] * xb[h * HW + w];
  }
  po[n] = acc;
}

// ---- implicit-GEMM conv, 2-phase pipelined, BM=256 BN=128 BK=64 ----
// 8 waves (4M x 2N), wave tile 64x64. Double-buffered LDS (2 x [A 32KB | B 16KB]).
// Per K-step: issue next-tile global_load_lds, then ds_read+MFMA current tile,
// then one __syncthreads (vmcnt(0) drain is covered by the compute phase).
__global__ __launch_bounds__(512, 2) void gemm_k(const unsigned short* __restrict__ xp,
                                                 const unsigned short* __restrict__ w_t,
                                                 const float* __restrict__ po,
                                                 const float* __restrict__ thresh,
                                                 const float* __restrict__ scale,
                                                 float* __restrict__ out) {
  __shared__ __align__(16) char sMem[2 * 49152];

  const int tid = threadIdx.x;
  const int lane = tid & 63;
  const int wid = tid >> 6;  // 0..7
  const int wm = wid >> 1;   // 0..3 (cout quadrant)
  const int wn = wid & 1;    // 0..1 (pixel half)

  // XCD-chunked swizzle: nwg=784, 784/8=98, 784%8==0 -> simple bijective form
  const int bid = blockIdx.x;
  const int n0 = ((bid & 7) * 98 + (bid >> 3)) * 128;

  // ---- staging addresses (linear LDS dest + inverse-swizzled global src) ----
  const int jr = lane >> 3;                // row within 8-row group
  const int sw = ((lane & 7) ^ jr) << 4;   // pre-swizzled 16B slot
  const char* xpc = (const char*)xp;
  const char* wtc = (const char*)w_t;
  int aSrc[4], ldsA[4];
#pragma unroll
  for (int i = 0; i < 4; ++i) {
    int r = wid * 32 + i * 8 + jr;         // cout row 0..255
    aSrc[i] = r * 9 * 256 + sw;
    ldsA[i] = (wid * 32 + i * 8) * 128;    // wave-uniform
  }
  int bSrc[2], ldsB[2];
#pragma unroll
  for (int i = 0; i < 2; ++i) {
    int r = wid * 16 + i * 8 + jr;         // pixel row 0..127
    int n = n0 + r;
    int b = n / HW2, rr = n - b * HW2;
    int h = rr / HW, w = rr - h * HW;
    bSrc[i] = ((b * PH + h + 1) * PH + (w + 1)) * 256 + sw;  // center tap
    ldsB[i] = 32768 + (wid * 16 + i * 8) * 128;
  }

  // ---- fragment read offsets (swizzled) ----
  int aro[4][2], bro[4][2];
#pragma unroll
  for (int i = 0; i < 4; ++i) {
#pragma unroll
    for (int ko = 0; ko < 2; ++ko) {
      int rowA = wm * 64 + i * 16 + (lane & 15);
      int rowB = wn * 64 + i * 16 + (lane & 15);
      int boc = ko * 64 + ((lane >> 4) << 4);
      aro[i][ko] = rowA * 128 + (boc ^ ((rowA & 7) << 4));
      bro[i][ko] = 32768 + rowB * 128 + (boc ^ ((rowB & 7) << 4));
    }
  }

  auto STAGE = [&](int buf, int step) {
    const int p = step >> 1;
    const int c0b = (step & 1) << 7;
    const int dy = p / 3 - 1, dx = p - (p / 3) * 3 - 1;
    const int offA = (p << 8) + c0b;
    const int offB = ((dy * PH + dx) << 8) + c0b;
    char* base = sMem + buf * 49152;
#pragma unroll
    for (int i = 0; i < 4; ++i) GLD_LDS16(wtc + aSrc[i] + offA, base + ldsA[i]);
#pragma unroll
    for (int i = 0; i < 2; ++i) GLD_LDS16(xpc + bSrc[i] + offB, base + ldsB[i]);
  };

  f32x4 acc[4][4] = {};

  STAGE(0, 0);
  __syncthreads();
  int cur = 0;
  for (int step = 0; step < 18; ++step) {
    if (step < 17) STAGE(cur ^ 1, step + 1);
    const char* base = sMem + cur * 49152;
#pragma unroll
    for (int ko = 0; ko < 2; ++ko) {
      f16x8 af[4], bfr[4];
#pragma unroll
      for (int i = 0; i < 4; ++i)
        af[i] = *reinterpret_cast<const f16x8*>(base + aro[i][ko]);
#pragma unroll
      for (int i = 0; i < 4; ++i)
        bfr[i] = *reinterpret_cast<const f16x8*>(base + bro[i][ko]);
      __builtin_amdgcn_s_setprio(1);
#pragma unroll
      for (int i = 0; i < 4; ++i)
#pragma unroll
        for (int j = 0; j < 4; ++j)
          acc[i][j] = __builtin_amdgcn_mfma_f32_16x16x32_f16(af[i], bfr[j], acc[i][j], 0, 0, 0);
      __builtin_amdgcn_s_setprio(0);
    }
    if (step < 17) {
      __syncthreads();  // vmcnt(0)+lgkmcnt(0)+barrier: next tile staged, reads drained
      cur ^= 1;
    }
  }

  const float sc = scale[0];
#pragma unroll
  for (int nj = 0; nj < 4; ++nj) {
    int n = n0 + wn * 64 + nj * 16 + (lane & 15);
    int b = n / HW2;
    int r = n - b * HW2;  // ho*56+wo
    float pv = po[n];
    float* op = out + (size_t)b * (COUT * HW2) + r;
#pragma unroll
    for (int mi = 0; mi < 4; ++mi) {
      int cl = wm * 64 + mi * 16 + ((lane >> 4) << 2);
#pragma unroll
      for (int q = 0; q < 4; ++q) {
        float cv = acc[mi][nj][q];
        float g = 1.f / (1.f + __expf(-sc * (cv - thresh[cl + q])));
        op[(size_t)(cl + q) * HW2] = cv + g * pv;
      }
    }
  }
}

extern "C" void kernel_launch(void* const* d_in, const int* in_sizes, int n_in,
                              void* d_out, int out_size, void* d_ws, size_t ws_size,
                              hipStream_t stream) {
  (void)in_sizes; (void)n_in; (void)out_size; (void)ws_size;
  const float* x      = (const float*)d_in[0];
  const float* core   = (const float*)d_in[1];
  const float* per    = (const float*)d_in[2];
  const float* thresh = (const float*)d_in[3];
  const float* scale  = (const float*)d_in[4];
  float* out = (float*)d_out;

  char* ws = (char*)d_ws;
  unsigned short* xp  = (unsigned short*)ws;                  // 32*58*58*128*2 = 27,557,888 B
  unsigned short* w_t = (unsigned short*)(ws + 27557888);     // 589,824 B
  float* xs           = (float*)(ws + 28147712);              // 401,408 B
  float* po           = (float*)(ws + 28549120);              // 401,408 B

  zero_halo<<<(NB * 228 * 16) / 256, 256, 0, stream>>>(xp);
  prep_x<<<NB * HW, 256, 0, stream>>>(x, xp, xs);
  prep_w<<<(COUT * 9 * CIN) / 256, 256, 0, stream>>>(core, w_t);
  periph_k<<<NPIX / 256, 256, 0, stream>>>(xs, per, po);
  gemm_k<<<NPIX / 128, 512, 0, stream>>>(xp, w_t, po, thresh, scale, out);
}

// Round 4
// 120.468 us; speedup vs baseline: 1.3571x; 1.0645x over previous
//
#include <hip/hip_runtime.h>

typedef __attribute__((__ext_vector_type__(8))) _Float16 f16x8;
typedef __attribute__((__ext_vector_type__(4))) float f32x4;
typedef __attribute__((__ext_vector_type__(4))) int i32x4;

#define HW 56
#define HW2 3136
#define CIN 128
#define COUT 256
#define NB 32
#define NPIX 100352  // 32*3136
#define PH 58        // padded spatial dim (1-px halo)

static __device__ __forceinline__ unsigned short f2h(float f) {
  _Float16 h = (_Float16)f;
  return __builtin_bit_cast(unsigned short, h);
}

#define GLD_LDS16(g, l)                                          \
  __builtin_amdgcn_global_load_lds(                              \
      (const __attribute__((address_space(1))) void*)(g),        \
      (__attribute__((address_space(3))) void*)(l), 16, 0, 0)

// ---- zero the 1-pixel halo of x_pad ----
__global__ __launch_bounds__(256) void zero_halo(unsigned short* __restrict__ xp) {
  int t = blockIdx.x * 256 + threadIdx.x;  // 32*228*16 threads
  int ck = t & 15;                          // 16B chunk in 256B pixel
  int pi = t >> 4;
  int b = pi / 228, r = pi - b * 228;
  int h, w;
  if (r < 58) { h = 0; w = r; }
  else if (r < 116) { h = 57; w = r - 58; }
  else { int q = r - 116; h = 1 + (q >> 1); w = (q & 1) * 57; }
  size_t off = (((size_t)(b * PH + h) * PH + w) << 8) + (ck << 4);
  *reinterpret_cast<i32x4*>((char*)xp + off) = (i32x4){0, 0, 0, 0};
}

// ---- prep_x: x NCHW f32 -> x_pad [32][58][58][128] f16 (interior), plus channel-sum xs ----
__global__ __launch_bounds__(256) void prep_x(const float* __restrict__ x,
                                              unsigned short* __restrict__ xp,
                                              float* __restrict__ xs) {
  __shared__ float tile[CIN * 57];  // [c][w], stride 57 kills bank conflicts
  const int bh = blockIdx.x;        // b*56 + h
  const float* src = x + (size_t)(bh / HW) * CIN * HW2 + (size_t)(bh % HW) * HW;
  for (int idx = threadIdx.x; idx < CIN * HW; idx += 256) {
    int c = idx / HW, w = idx - c * HW;
    tile[c * 57 + w] = src[(size_t)c * HW2 + w];
  }
  __syncthreads();
  unsigned short* dst =
      xp + (((size_t)(bh / HW) * PH + (bh % HW) + 1) * PH + 1) * CIN;
  for (int idx = threadIdx.x; idx < HW * (CIN / 2); idx += 256) {
    int w = idx >> 6;         // pixel within row
    int c = (idx & 63) << 1;  // channel pair
    unsigned lo = f2h(tile[c * 57 + w]);
    unsigned hi = f2h(tile[(c + 1) * 57 + w]);
    *reinterpret_cast<unsigned*>(&dst[w * CIN + c]) = lo | (hi << 16);
  }
  if (threadIdx.x < HW) {
    float s = 0.f;
    for (int c = 0; c < CIN; ++c) s += tile[c * 57 + threadIdx.x];
    xs[(size_t)bh * HW + threadIdx.x] = s;
  }
}

// ---- prep_w: core [COUT][CIN][3][3] f32 -> w_t [COUT][9][CIN] f16 ----
__global__ __launch_bounds__(256) void prep_w(const float* __restrict__ core,
                                              unsigned short* __restrict__ w_t) {
  int i = blockIdx.x * 256 + threadIdx.x;  // < 256*9*128
  int c = i & 127;
  int p = (i >> 7) % 9;
  int m = i / (9 * 128);
  w_t[i] = f2h(core[(size_t)(m * CIN + c) * 9 + p]);
}

// ---- periphery stencil on xs ----
__global__ __launch_bounds__(256) void periph_k(const float* __restrict__ xs,
                                                const float* __restrict__ per,
                                                float* __restrict__ po) {
  int n = blockIdx.x * 256 + threadIdx.x;
  int b = n / HW2, r = n - b * HW2;
  int ho = r / HW, wo = r - ho * HW;
  const float* xb = xs + (size_t)b * HW2;
  const int pdy[16] = {0,0,0,0,0,1,1,2,2,3,3,4,4,4,4,4};
  const int pdx[16] = {0,1,2,3,4,0,4,0,4,0,4,0,1,2,3,4};
  float acc = 0.f;
#pragma unroll
  for (int t = 0; t < 16; ++t) {
    int h = ho + pdy[t] - 2, w = wo + pdx[t] - 2;
    if ((unsigned)h < HW && (unsigned)w < HW) acc += per[t] * xb[h * HW + w];
  }
  po[n] = acc;
}

// ---- implicit-GEMM conv, counted-vmcnt pipeline, BM=256 BN=256 BK=64 ----
// 8 waves (2M x 4N), wave tile 128x64. Double-buffered LDS (2 x 64KB), raw
// s_barrier + s_waitcnt vmcnt(8): the wait covers loads issued one full
// K-step (~2500 cyc) earlier -> stage latency fully hidden; NO vmcnt(0)
// drain in the main loop (T4, m218: counted-vs-drain0 = +38-73%).
// Race discipline: B1 separates reads(s-1) from STAGE(s+1) writes into that
// buffer; vmcnt(8) BEFORE B2 guarantees all waves' stage(s) landed before
// any wave's ds_reads of buffer s.
__global__ __launch_bounds__(512, 2) void gemm_k(const unsigned short* __restrict__ xp,
                                                 const unsigned short* __restrict__ w_t,
                                                 const float* __restrict__ po,
                                                 const float* __restrict__ thresh,
                                                 const float* __restrict__ scale,
                                                 float* __restrict__ out) {
  __shared__ __align__(16) char sMem[2 * 65536 + 1024];

  const int tid = threadIdx.x;
  const int lane = tid & 63;
  const int wid = tid >> 6;  // 0..7
  const int wm = wid >> 2;   // 0..1 (cout half)
  const int wn = wid & 3;    // 0..3 (pixel quarter)

  // XCD-chunked bijective swizzle: nwg=392=8*49
  const int bid = blockIdx.x;
  const int n0 = ((bid & 7) * 49 + (bid >> 3)) << 8;

  float* sTh = (float*)(sMem + 131072);
  if (tid < 256) sTh[tid] = thresh[tid];

  // ---- staging addresses (linear LDS dest + inverse-swizzled global src) ----
  const int slot = tid & 7;
  const int trow = tid >> 3;               // 0..63
  const int sw = (slot ^ (trow & 7)) << 4; // pre-swizzled 16B slot
  const char* xpc = (const char*)xp;
  const char* wtc = (const char*)w_t;
  int aOff[4], bOff[4];
#pragma unroll
  for (int q = 0; q < 4; ++q) {
    int row = q * 64 + trow;               // 0..255
    aOff[q] = row * (9 * 256) + sw;        // w_t row stride = 9*128ch*2B
    int n = n0 + row;
    int b = n / HW2, rr = n - b * HW2;
    int h = rr / HW, w = rr - h * HW;
    bOff[q] = ((b * PH + h + 1) * PH + (w + 1)) * 256 + sw;  // center tap
  }
  const int ldsw = wid * 1024;  // wave-uniform; lane*16 appended by HW

  // ---- fragment read offsets (swizzled) ----
  int aro[8][2], bro[4][2];
#pragma unroll
  for (int i = 0; i < 8; ++i)
#pragma unroll
    for (int ko = 0; ko < 2; ++ko) {
      int rowA = wm * 128 + i * 16 + (lane & 15);
      int boc = ko * 64 + ((lane >> 4) << 4);
      aro[i][ko] = rowA * 128 + (boc ^ ((rowA & 7) << 4));
    }
#pragma unroll
  for (int j = 0; j < 4; ++j)
#pragma unroll
    for (int ko = 0; ko < 2; ++ko) {
      int rowB = wn * 64 + j * 16 + (lane & 15);
      int boc = ko * 64 + ((lane >> 4) << 4);
      bro[j][ko] = 32768 + rowB * 128 + (boc ^ ((rowB & 7) << 4));
    }

  auto STAGE = [&](int buf, int step) {
    const int p = step >> 1;
    const int c0b = (step & 1) << 7;
    const int dy = p / 3 - 1, dx = p - (p / 3) * 3 - 1;
    const int offA = (p << 8) + c0b;
    const int offB = ((dy * PH + dx) << 8) + c0b;
    char* base = sMem + buf * 65536;
#pragma unroll
    for (int q = 0; q < 4; ++q)
      GLD_LDS16(wtc + aOff[q] + offA, base + ldsw + q * 8192);
#pragma unroll
    for (int q = 0; q < 4; ++q)
      GLD_LDS16(xpc + bOff[q] + offB, base + 32768 + ldsw + q * 8192);
  };

  f32x4 acc[8][4] = {};

  STAGE(0, 0);
  __syncthreads();  // prologue: drains stage(0), publishes sTh

#pragma unroll
  for (int s = 0; s < 18; ++s) {
    const char* base = sMem + (s & 1) * 65536;
    __builtin_amdgcn_s_barrier();  // B1: all reads(s-1) complete
    if (s < 17) {
      STAGE((s + 1) & 1, s + 1);
      asm volatile("s_waitcnt vmcnt(8)" ::: "memory");  // stage(s) landed
    } else {
      asm volatile("s_waitcnt vmcnt(0)" ::: "memory");
    }
    __builtin_amdgcn_s_barrier();  // B2: everyone's stage(s) landed
    f16x8 bfr[4][2];
#pragma unroll
    for (int j = 0; j < 4; ++j)
#pragma unroll
      for (int ko = 0; ko < 2; ++ko)
        bfr[j][ko] = *reinterpret_cast<const f16x8*>(base + bro[j][ko]);
#pragma unroll
    for (int i = 0; i < 8; ++i) {
      f16x8 a0 = *reinterpret_cast<const f16x8*>(base + aro[i][0]);
      f16x8 a1 = *reinterpret_cast<const f16x8*>(base + aro[i][1]);
      __builtin_amdgcn_s_setprio(1);
#pragma unroll
      for (int j = 0; j < 4; ++j) {
        acc[i][j] = __builtin_amdgcn_mfma_f32_16x16x32_f16(a0, bfr[j][0], acc[i][j], 0, 0, 0);
        acc[i][j] = __builtin_amdgcn_mfma_f32_16x16x32_f16(a1, bfr[j][1], acc[i][j], 0, 0, 0);
      }
      __builtin_amdgcn_s_setprio(0);
    }
  }

  const float sc = scale[0];
#pragma unroll
  for (int j = 0; j < 4; ++j) {
    int n = n0 + wn * 64 + j * 16 + (lane & 15);
    int b = n / HW2;
    int r = n - b * HW2;  // ho*56+wo
    float pv = po[n];
    float* op = out + (size_t)b * (COUT * HW2) + r;
#pragma unroll
    for (int i = 0; i < 8; ++i) {
      int cl = wm * 128 + i * 16 + ((lane >> 4) << 2);
#pragma unroll
      for (int q = 0; q < 4; ++q) {
        float cv = acc[i][j][q];
        float g = 1.f / (1.f + __expf(-sc * (cv - sTh[cl + q])));
        op[(size_t)(cl + q) * HW2] = cv + g * pv;
      }
    }
  }
}

extern "C" void kernel_launch(void* const* d_in, const int* in_sizes, int n_in,
                              void* d_out, int out_size, void* d_ws, size_t ws_size,
                              hipStream_t stream) {
  (void)in_sizes; (void)n_in; (void)out_size; (void)ws_size;
  const float* x      = (const float*)d_in[0];
  const float* core   = (const float*)d_in[1];
  const float* per    = (const float*)d_in[2];
  const float* thresh = (const float*)d_in[3];
  const float* scale  = (const float*)d_in[4];
  float* out = (float*)d_out;

  char* ws = (char*)d_ws;
  unsigned short* xp  = (unsigned short*)ws;                  // 32*58*58*128*2 = 27,557,888 B
  unsigned short* w_t = (unsigned short*)(ws + 27557888);     // 589,824 B
  float* xs           = (float*)(ws + 28147712);              // 401,408 B
  float* po           = (float*)(ws + 28549120);              // 401,408 B

  zero_halo<<<(NB * 228 * 16) / 256, 256, 0, stream>>>(xp);
  prep_x<<<NB * HW, 256, 0, stream>>>(x, xp, xs);
  prep_w<<<(COUT * 9 * CIN) / 256, 256, 0, stream>>>(core, w_t);
  periph_k<<<NPIX / 256, 256, 0, stream>>>(xs, per, po);
  gemm_k<<<NPIX / 256, 512, 0, stream>>>(xp, w_t, po, thresh, scale, out);
}